// Round 1
// baseline (955.096 us; speedup 1.0000x reference)
//
#include <hip/hip_runtime.h>

// MalleConv: all f32.
// Inputs: x(4,32,512,512), pa_w(4,2,32,32,3,3), pa_b(4,2,32),
//         exp_w(320,32,1,1), exp_b(320), pw_w(32,32,1,1), pw_b(32)
// Output: (4,32,512,512) f32

#define BATCH 4
#define NCH 32

// ---- weight transpose: (8,co,ci,9) -> (8,ci,9,co) for uniform contiguous co-reads
__global__ void transpose_w_kernel(const float* __restrict__ pa_w, float* __restrict__ wt) {
  int i = blockIdx.x * 256 + threadIdx.x;
  if (i >= 8 * 32 * 32 * 9) return;
  int tap = i % 9; int t = i / 9;
  int ci = t & 31; t >>= 5;
  int co = t & 31; int layer = t >> 5;
  wt[((layer * 32 + ci) * 9 + tap) * 32 + co] = pa_w[i];
}

// ---- avgpool k=4: (B,C,512,512) -> (B,C,128,128)
__global__ void avgpool4_kernel(const float* __restrict__ x, float* __restrict__ out) {
  int idx = blockIdx.x * 256 + threadIdx.x;
  if (idx >= BATCH * NCH * 128 * 128) return;
  int ow = idx & 127; int t = idx >> 7; int oh = t & 127; int bc = t >> 7;
  const float* src = x + ((size_t)(bc * 512 + oh * 4)) * 512 + ow * 4;
  float s = 0.f;
#pragma unroll
  for (int r = 0; r < 4; r++) {
    float4 v = *reinterpret_cast<const float4*>(src + (size_t)r * 512);
    s += v.x + v.y + v.z + v.w;
  }
  out[idx] = s * 0.0625f;
}

// ---- avgpool k=2: (B,C,128,128) -> (B,C,64,64)
__global__ void avgpool2_kernel(const float* __restrict__ in, float* __restrict__ out) {
  int idx = blockIdx.x * 256 + threadIdx.x;
  if (idx >= BATCH * NCH * 64 * 64) return;
  int ow = idx & 63; int t = idx >> 6; int oh = t & 63; int bc = t >> 6;
  const float* src = in + (size_t)(bc * 128 + oh * 2) * 128 + ow * 2;
  float2 a = *reinterpret_cast<const float2*>(src);
  float2 b = *reinterpret_cast<const float2*>(src + 128);
  out[idx] = (a.x + a.y + b.x + b.y) * 0.25f;
}

// ---- conv3x3 (same padding), C=32->32, optional leaky-relu on output, optional residual add.
// wt layout: (ci,9,co) so the co-inner loop is uniform+contiguous -> scalar loads.
template <int HS, bool RELU, bool RES>
__global__ __launch_bounds__(256) void conv3x3_kernel(
    const float* __restrict__ in, const float* __restrict__ wt,
    const float* __restrict__ bias, const float* __restrict__ res,
    float* __restrict__ out) {
  constexpr int TILES = HS / 16;
  __shared__ float s_in[32][18][18];
  int blk = blockIdx.x;
  int b = blk / (TILES * TILES); int t = blk % (TILES * TILES);
  int ty = t / TILES, tx = t % TILES;
  int tid = threadIdx.x;
  int gx0 = tx * 16 - 1, gy0 = ty * 16 - 1;
  const float* inb = in + (size_t)b * 32 * HS * HS;

  for (int i = tid; i < 32 * 18 * 18; i += 256) {
    int ci = i / 324; int r = i - ci * 324;
    int row = r / 18; int col = r - row * 18;
    int gy = gy0 + row, gx = gx0 + col;
    float v = 0.f;
    if (gy >= 0 && gy < HS && gx >= 0 && gx < HS)
      v = inb[((size_t)ci * HS + gy) * HS + gx];
    s_in[ci][row][col] = v;
  }
  __syncthreads();

  int px = tid & 15, py = tid >> 4;
  float acc[32];
#pragma unroll
  for (int o = 0; o < 32; o++) acc[o] = bias[o];

  for (int ci = 0; ci < 32; ci++) {
    float v[9];
#pragma unroll
    for (int di = 0; di < 3; di++)
#pragma unroll
      for (int dj = 0; dj < 3; dj++)
        v[di * 3 + dj] = s_in[ci][py + di][px + dj];
#pragma unroll
    for (int tap = 0; tap < 9; tap++) {
      const float* wrow = wt + (ci * 9 + tap) * 32;
#pragma unroll
      for (int o = 0; o < 32; o++)
        acc[o] = fmaf(v[tap], wrow[o], acc[o]);
    }
  }

  int gy = ty * 16 + py, gx = tx * 16 + px;
#pragma unroll
  for (int o = 0; o < 32; o++) {
    float r2 = acc[o];
    if (RELU) r2 = r2 > 0.f ? r2 : 0.01f * r2;
    size_t oi = (((size_t)b * 32 + o) * HS + gy) * HS + gx;
    if (RES) r2 += res[oi];
    out[oi] = r2;
  }
}

// ---- expander 1x1 (32->320) + tanh + transpose to (B,C,Hb,Wb,10)
__global__ void expander_kernel(const float* __restrict__ feat, const float* __restrict__ ew,
                                const float* __restrict__ eb, float* __restrict__ wmap) {
  int idx = blockIdx.x * 256 + threadIdx.x;
  if (idx >= BATCH * 64 * 64) return;
  int wb = idx & 63; int t = idx >> 6; int hb = t & 63; int b = t >> 6;
  float f[32];
#pragma unroll
  for (int ci = 0; ci < 32; ci++)
    f[ci] = feat[(((size_t)b * 32 + ci) * 64 + hb) * 64 + wb];
  for (int c = 0; c < 32; c++) {
    float* dst = wmap + ((((size_t)b * 32 + c) * 64 + hb) * 64 + wb) * 10;
#pragma unroll
    for (int kt = 0; kt < 10; kt++) {
      int o = c * 10 + kt;
      float s = eb[o];
#pragma unroll
      for (int ci = 0; ci < 32; ci++)
        s = fmaf(f[ci], ew[o * 32 + ci], s);
      dst[kt] = tanhf(s);
    }
  }
}

// ---- fused flying_conv + final 1x1 conv
__global__ __launch_bounds__(256) void fused_fly_pw_kernel(
    const float* __restrict__ x, const float* __restrict__ wmap,
    const float* __restrict__ pw_w, const float* __restrict__ pw_b,
    float* __restrict__ out) {
  int idx = blockIdx.x * 256 + threadIdx.x;  // B*512*512 threads
  int w = idx & 511; int t = idx >> 9; int h = t & 511; int b = t >> 9;
  int hb = h >> 3, wb = w >> 3;
  float acc[32];
#pragma unroll
  for (int o = 0; o < 32; o++) acc[o] = pw_b[o];

  for (int c = 0; c < 32; c++) {
    const float* xc = x + ((size_t)(b * 32 + c)) * 512 * 512;
    const float* wv = wmap + ((((size_t)b * 32 + c) * 64 + hb) * 64 + wb) * 10;
    float wr[10];
#pragma unroll
    for (int k = 0; k < 5; k++) {
      float2 p = *reinterpret_cast<const float2*>(wv + 2 * k);
      wr[2 * k] = p.x; wr[2 * k + 1] = p.y;
    }
    float fly = wr[9];  // bias
#pragma unroll
    for (int di = 0; di < 3; di++) {
      int hh = h + di - 1;
      if (hh < 0 || hh >= 512) continue;
      const float* row = xc + (size_t)hh * 512;
#pragma unroll
      for (int dj = 0; dj < 3; dj++) {
        int ww = w + dj - 1;
        if (ww < 0 || ww >= 512) continue;
        fly = fmaf(row[ww], wr[di * 3 + dj], fly);
      }
    }
#pragma unroll
    for (int o = 0; o < 32; o++)
      acc[o] = fmaf(fly, pw_w[o * 32 + c], acc[o]);
  }
#pragma unroll
  for (int o = 0; o < 32; o++)
    out[(((size_t)b * 32 + o) * 512 + h) * 512 + w] = acc[o];
}

extern "C" void kernel_launch(void* const* d_in, const int* in_sizes, int n_in,
                              void* d_out, int out_size, void* d_ws, size_t ws_size,
                              hipStream_t stream) {
  const float* x     = (const float*)d_in[0];
  const float* pa_w  = (const float*)d_in[1];
  const float* pa_b  = (const float*)d_in[2];
  const float* exp_w = (const float*)d_in[3];
  const float* exp_b = (const float*)d_in[4];
  const float* pw_w  = (const float*)d_in[5];
  const float* pw_b  = (const float*)d_in[6];
  float* out = (float*)d_out;
  float* ws  = (float*)d_ws;

  float* feat0 = ws;                 // 4*32*128*128 = 2,097,152
  float* tmpA  = feat0 + 2097152;    // 2,097,152
  float* feat1 = tmpA + 2097152;     // 4*32*64*64 = 524,288
  float* tmpB  = feat1 + 524288;     // 524,288
  float* wmap  = tmpB + 524288;      // 4*32*64*64*10 = 5,242,880
  float* wt    = wmap + 5242880;     // 73,728

  hipLaunchKernelGGL(transpose_w_kernel, dim3(288), dim3(256), 0, stream, pa_w, wt);
  hipLaunchKernelGGL(avgpool4_kernel, dim3(8192), dim3(256), 0, stream, x, feat0);

  for (int i = 0; i < 2; i++) {
    const float* w1 = wt + (size_t)(i * 2 + 0) * 9216;
    const float* b1 = pa_b + (i * 2 + 0) * 32;
    const float* w2 = wt + (size_t)(i * 2 + 1) * 9216;
    const float* b2 = pa_b + (i * 2 + 1) * 32;
    hipLaunchKernelGGL((conv3x3_kernel<128, true, false>), dim3(BATCH * 64), dim3(256), 0, stream,
                       feat0, w1, b1, nullptr, tmpA);
    hipLaunchKernelGGL((conv3x3_kernel<128, false, true>), dim3(BATCH * 64), dim3(256), 0, stream,
                       tmpA, w2, b2, feat0, feat0);
  }

  hipLaunchKernelGGL(avgpool2_kernel, dim3(2048), dim3(256), 0, stream, feat0, feat1);

  for (int i = 2; i < 4; i++) {
    const float* w1 = wt + (size_t)(i * 2 + 0) * 9216;
    const float* b1 = pa_b + (i * 2 + 0) * 32;
    const float* w2 = wt + (size_t)(i * 2 + 1) * 9216;
    const float* b2 = pa_b + (i * 2 + 1) * 32;
    hipLaunchKernelGGL((conv3x3_kernel<64, true, false>), dim3(BATCH * 16), dim3(256), 0, stream,
                       feat1, w1, b1, nullptr, tmpB);
    hipLaunchKernelGGL((conv3x3_kernel<64, false, true>), dim3(BATCH * 16), dim3(256), 0, stream,
                       tmpB, w2, b2, feat1, feat1);
  }

  hipLaunchKernelGGL(expander_kernel, dim3(64), dim3(256), 0, stream, feat1, exp_w, exp_b, wmap);
  hipLaunchKernelGGL(fused_fly_pw_kernel, dim3(4096), dim3(256), 0, stream,
                     x, wmap, pw_w, pw_b, out);
}

// Round 2
// 813.567 us; speedup vs baseline: 1.1740x; 1.1740x over previous
//
#include <hip/hip_runtime.h>

// MalleConv: all f32.
// Inputs: x(4,32,512,512), pa_w(4,2,32,32,3,3), pa_b(4,2,32),
//         exp_w(320,32,1,1), exp_b(320), pw_w(32,32,1,1), pw_b(32)
// Output: (4,32,512,512) f32

#define BATCH 4
#define NCH 32

// ---- weight transpose: (8,co,ci,9) -> (8,ci,9,co) for uniform contiguous co-reads
__global__ void transpose_w_kernel(const float* __restrict__ pa_w, float* __restrict__ wt) {
  int i = blockIdx.x * 256 + threadIdx.x;
  if (i >= 8 * 32 * 32 * 9) return;
  int tap = i % 9; int t = i / 9;
  int ci = t & 31; t >>= 5;
  int co = t & 31; int layer = t >> 5;
  wt[((layer * 32 + ci) * 9 + tap) * 32 + co] = pa_w[i];
}

// ---- expander weight transpose: (320,32) -> (32,320)
__global__ void transpose_ew_kernel(const float* __restrict__ ew, float* __restrict__ ewt) {
  int i = blockIdx.x * 256 + threadIdx.x;
  if (i >= 320 * 32) return;
  int ci = i & 31; int o = i >> 5;
  ewt[ci * 320 + o] = ew[i];
}

// ---- avgpool k=4: (B,C,512,512) -> (B,C,128,128)
__global__ void avgpool4_kernel(const float* __restrict__ x, float* __restrict__ out) {
  int idx = blockIdx.x * 256 + threadIdx.x;
  if (idx >= BATCH * NCH * 128 * 128) return;
  int ow = idx & 127; int t = idx >> 7; int oh = t & 127; int bc = t >> 7;
  const float* src = x + ((size_t)(bc * 512 + oh * 4)) * 512 + ow * 4;
  float s = 0.f;
#pragma unroll
  for (int r = 0; r < 4; r++) {
    float4 v = *reinterpret_cast<const float4*>(src + (size_t)r * 512);
    s += v.x + v.y + v.z + v.w;
  }
  out[idx] = s * 0.0625f;
}

// ---- avgpool k=2: (B,C,128,128) -> (B,C,64,64)
__global__ void avgpool2_kernel(const float* __restrict__ in, float* __restrict__ out) {
  int idx = blockIdx.x * 256 + threadIdx.x;
  if (idx >= BATCH * NCH * 64 * 64) return;
  int ow = idx & 63; int t = idx >> 6; int oh = t & 63; int bc = t >> 6;
  const float* src = in + (size_t)(bc * 128 + oh * 2) * 128 + ow * 2;
  float2 a = *reinterpret_cast<const float2*>(src);
  float2 b = *reinterpret_cast<const float2*>(src + 128);
  out[idx] = (a.x + a.y + b.x + b.y) * 0.25f;
}

// ---- conv3x3 (same padding), C=32->32, optional leaky-relu on output, optional residual add.
// wt layout: (ci,9,co) so the co-inner loop is uniform+contiguous -> scalar loads.
template <int HS, bool RELU, bool RES>
__global__ __launch_bounds__(256) void conv3x3_kernel(
    const float* __restrict__ in, const float* __restrict__ wt,
    const float* __restrict__ bias, const float* __restrict__ res,
    float* __restrict__ out) {
  constexpr int TILES = HS / 16;
  __shared__ float s_in[32][18][18];
  int blk = blockIdx.x;
  int b = blk / (TILES * TILES); int t = blk % (TILES * TILES);
  int ty = t / TILES, tx = t % TILES;
  int tid = threadIdx.x;
  int gx0 = tx * 16 - 1, gy0 = ty * 16 - 1;
  const float* inb = in + (size_t)b * 32 * HS * HS;

  for (int i = tid; i < 32 * 18 * 18; i += 256) {
    int ci = i / 324; int r = i - ci * 324;
    int row = r / 18; int col = r - row * 18;
    int gy = gy0 + row, gx = gx0 + col;
    float v = 0.f;
    if (gy >= 0 && gy < HS && gx >= 0 && gx < HS)
      v = inb[((size_t)ci * HS + gy) * HS + gx];
    s_in[ci][row][col] = v;
  }
  __syncthreads();

  int px = tid & 15, py = tid >> 4;
  float acc[32];
#pragma unroll
  for (int o = 0; o < 32; o++) acc[o] = bias[o];

  for (int ci = 0; ci < 32; ci++) {
    float v[9];
#pragma unroll
    for (int di = 0; di < 3; di++)
#pragma unroll
      for (int dj = 0; dj < 3; dj++)
        v[di * 3 + dj] = s_in[ci][py + di][px + dj];
#pragma unroll
    for (int tap = 0; tap < 9; tap++) {
      const float* wrow = wt + (ci * 9 + tap) * 32;
#pragma unroll
      for (int o = 0; o < 32; o++)
        acc[o] = fmaf(v[tap], wrow[o], acc[o]);
    }
  }

  int gy = ty * 16 + py, gx = tx * 16 + px;
#pragma unroll
  for (int o = 0; o < 32; o++) {
    float r2 = acc[o];
    if (RELU) r2 = r2 > 0.f ? r2 : 0.01f * r2;
    size_t oi = (((size_t)b * 32 + o) * HS + gy) * HS + gx;
    if (RES) r2 += res[oi];
    out[oi] = r2;
  }
}

// ---- expander 1x1 (32->320) + tanh, one thread per (pixel, output).
// ewt layout: (ci, o). wmap layout: (B, Hb, Wb, C, 10) -- pixel-major, coalesced write.
__global__ __launch_bounds__(256) void expander_kernel(
    const float* __restrict__ feat, const float* __restrict__ ewt,
    const float* __restrict__ eb, float* __restrict__ wmap) {
  int idx = blockIdx.x * 256 + threadIdx.x;
  if (idx >= BATCH * 64 * 64 * 320) return;
  int o = idx % 320;
  int pix = idx / 320;
  int wb = pix & 63; int t = pix >> 6; int hb = t & 63; int b = t >> 6;
  const float* fp = feat + (size_t)b * 32 * 64 * 64 + hb * 64 + wb;
  float s = eb[o];
#pragma unroll
  for (int ci = 0; ci < 32; ci++)
    s = fmaf(fp[(size_t)ci * 4096], ewt[ci * 320 + o], s);
  wmap[idx] = tanhf(s);
}

// ---- fused flying_conv + final 1x1 conv
// wmap layout: (B, Hb, Wb, C, 10)
__global__ __launch_bounds__(256) void fused_fly_pw_kernel(
    const float* __restrict__ x, const float* __restrict__ wmap,
    const float* __restrict__ pw_w, const float* __restrict__ pw_b,
    float* __restrict__ out) {
  int idx = blockIdx.x * 256 + threadIdx.x;  // B*512*512 threads
  int w = idx & 511; int t = idx >> 9; int h = t & 511; int b = t >> 9;
  int hb = h >> 3, wb = w >> 3;
  float acc[32];
#pragma unroll
  for (int o = 0; o < 32; o++) acc[o] = pw_b[o];

  const float* wblk = wmap + (((size_t)(b * 64 + hb) * 64 + wb) * 32) * 10;
  for (int c = 0; c < 32; c++) {
    const float* xc = x + ((size_t)(b * 32 + c)) * 512 * 512;
    const float* wv = wblk + c * 10;
    float wr[10];
#pragma unroll
    for (int k = 0; k < 5; k++) {
      float2 p = *reinterpret_cast<const float2*>(wv + 2 * k);
      wr[2 * k] = p.x; wr[2 * k + 1] = p.y;
    }
    float fly = wr[9];  // bias
#pragma unroll
    for (int di = 0; di < 3; di++) {
      int hh = h + di - 1;
      if (hh < 0 || hh >= 512) continue;
      const float* row = xc + (size_t)hh * 512;
#pragma unroll
      for (int dj = 0; dj < 3; dj++) {
        int ww = w + dj - 1;
        if (ww < 0 || ww >= 512) continue;
        fly = fmaf(row[ww], wr[di * 3 + dj], fly);
      }
    }
#pragma unroll
    for (int o = 0; o < 32; o++)
      acc[o] = fmaf(fly, pw_w[o * 32 + c], acc[o]);
  }
#pragma unroll
  for (int o = 0; o < 32; o++)
    out[(((size_t)b * 32 + o) * 512 + h) * 512 + w] = acc[o];
}

extern "C" void kernel_launch(void* const* d_in, const int* in_sizes, int n_in,
                              void* d_out, int out_size, void* d_ws, size_t ws_size,
                              hipStream_t stream) {
  const float* x     = (const float*)d_in[0];
  const float* pa_w  = (const float*)d_in[1];
  const float* pa_b  = (const float*)d_in[2];
  const float* exp_w = (const float*)d_in[3];
  const float* exp_b = (const float*)d_in[4];
  const float* pw_w  = (const float*)d_in[5];
  const float* pw_b  = (const float*)d_in[6];
  float* out = (float*)d_out;
  float* ws  = (float*)d_ws;

  float* feat0 = ws;                 // 4*32*128*128 = 2,097,152
  float* tmpA  = feat0 + 2097152;    // 2,097,152
  float* feat1 = tmpA + 2097152;     // 4*32*64*64 = 524,288
  float* tmpB  = feat1 + 524288;     // 524,288
  float* wmap  = tmpB + 524288;      // 4*64*64*32*10 = 5,242,880
  float* wt    = wmap + 5242880;     // 73,728
  float* ewt   = wt + 73728;         // 10,240

  hipLaunchKernelGGL(transpose_w_kernel, dim3(288), dim3(256), 0, stream, pa_w, wt);
  hipLaunchKernelGGL(transpose_ew_kernel, dim3(40), dim3(256), 0, stream, exp_w, ewt);
  hipLaunchKernelGGL(avgpool4_kernel, dim3(8192), dim3(256), 0, stream, x, feat0);

  for (int i = 0; i < 2; i++) {
    const float* w1 = wt + (size_t)(i * 2 + 0) * 9216;
    const float* b1 = pa_b + (i * 2 + 0) * 32;
    const float* w2 = wt + (size_t)(i * 2 + 1) * 9216;
    const float* b2 = pa_b + (i * 2 + 1) * 32;
    hipLaunchKernelGGL((conv3x3_kernel<128, true, false>), dim3(BATCH * 64), dim3(256), 0, stream,
                       feat0, w1, b1, nullptr, tmpA);
    hipLaunchKernelGGL((conv3x3_kernel<128, false, true>), dim3(BATCH * 64), dim3(256), 0, stream,
                       tmpA, w2, b2, feat0, feat0);
  }

  hipLaunchKernelGGL(avgpool2_kernel, dim3(2048), dim3(256), 0, stream, feat0, feat1);

  for (int i = 2; i < 4; i++) {
    const float* w1 = wt + (size_t)(i * 2 + 0) * 9216;
    const float* b1 = pa_b + (i * 2 + 0) * 32;
    const float* w2 = wt + (size_t)(i * 2 + 1) * 9216;
    const float* b2 = pa_b + (i * 2 + 1) * 32;
    hipLaunchKernelGGL((conv3x3_kernel<64, true, false>), dim3(BATCH * 16), dim3(256), 0, stream,
                       feat1, w1, b1, nullptr, tmpB);
    hipLaunchKernelGGL((conv3x3_kernel<64, false, true>), dim3(BATCH * 16), dim3(256), 0, stream,
                       tmpB, w2, b2, feat1, feat1);
  }

  hipLaunchKernelGGL(expander_kernel, dim3(20480), dim3(256), 0, stream, feat1, ewt, exp_b, wmap);
  hipLaunchKernelGGL(fused_fly_pw_kernel, dim3(4096), dim3(256), 0, stream,
                     x, wmap, pw_w, pw_b, out);
}

// Round 3
// 577.751 us; speedup vs baseline: 1.6531x; 1.4082x over previous
//
#include <hip/hip_runtime.h>

// MalleConv: all f32.
// Inputs: x(4,32,512,512), pa_w(4,2,32,32,3,3), pa_b(4,2,32),
//         exp_w(320,32,1,1), exp_b(320), pw_w(32,32,1,1), pw_b(32)
// Output: (4,32,512,512) f32

#define BATCH 4
#define NCH 32

// ---- weight transpose: (8,co,ci,9) -> (8,ci,9,co) for uniform contiguous co-reads
__global__ void transpose_w_kernel(const float* __restrict__ pa_w, float* __restrict__ wt) {
  int i = blockIdx.x * 256 + threadIdx.x;
  if (i >= 8 * 32 * 32 * 9) return;
  int tap = i % 9; int t = i / 9;
  int ci = t & 31; t >>= 5;
  int co = t & 31; int layer = t >> 5;
  wt[((layer * 32 + ci) * 9 + tap) * 32 + co] = pa_w[i];
}

// ---- expander weight transpose: (320,32) -> (32,320)
__global__ void transpose_ew_kernel(const float* __restrict__ ew, float* __restrict__ ewt) {
  int i = blockIdx.x * 256 + threadIdx.x;
  if (i >= 320 * 32) return;
  int ci = i & 31; int o = i >> 5;
  ewt[ci * 320 + o] = ew[i];
}

// ---- pw weight transpose: (32,32) [o][c] -> (32,32) [c][o]
__global__ void transpose_pw_kernel(const float* __restrict__ pw, float* __restrict__ pwt) {
  int i = threadIdx.x + blockIdx.x * 256;
  if (i >= 1024) return;
  int c = i & 31; int o = i >> 5;
  pwt[c * 32 + o] = pw[i];
}

// ---- avgpool k=4: (B,C,512,512) -> (B,C,128,128)
__global__ void avgpool4_kernel(const float* __restrict__ x, float* __restrict__ out) {
  int idx = blockIdx.x * 256 + threadIdx.x;
  if (idx >= BATCH * NCH * 128 * 128) return;
  int ow = idx & 127; int t = idx >> 7; int oh = t & 127; int bc = t >> 7;
  const float* src = x + ((size_t)(bc * 512 + oh * 4)) * 512 + ow * 4;
  float s = 0.f;
#pragma unroll
  for (int r = 0; r < 4; r++) {
    float4 v = *reinterpret_cast<const float4*>(src + (size_t)r * 512);
    s += v.x + v.y + v.z + v.w;
  }
  out[idx] = s * 0.0625f;
}

// ---- avgpool k=2: (B,C,128,128) -> (B,C,64,64)
__global__ void avgpool2_kernel(const float* __restrict__ in, float* __restrict__ out) {
  int idx = blockIdx.x * 256 + threadIdx.x;
  if (idx >= BATCH * NCH * 64 * 64) return;
  int ow = idx & 63; int t = idx >> 6; int oh = t & 63; int bc = t >> 6;
  const float* src = in + (size_t)(bc * 128 + oh * 2) * 128 + ow * 2;
  float2 a = *reinterpret_cast<const float2*>(src);
  float2 b = *reinterpret_cast<const float2*>(src + 128);
  out[idx] = (a.x + a.y + b.x + b.y) * 0.25f;
}

// ---- conv3x3 (same padding), C=32->NCO per block, optional leaky-relu, optional residual.
// wt layout: (ci,9,co). GROUPS = 32/NCO blocks per tile for output-channel parallelism.
template <int HS, int NCO, bool RELU, bool RES>
__global__ __launch_bounds__(256) void conv3x3_kernel(
    const float* __restrict__ in, const float* __restrict__ wt,
    const float* __restrict__ bias, const float* __restrict__ res,
    float* __restrict__ out) {
  constexpr int TILES = HS / 16;
  constexpr int GROUPS = 32 / NCO;
  __shared__ float s_in[32][18][18];
  int blk = blockIdx.x;
  int g = blk % GROUPS; int rest = blk / GROUPS;
  int b = rest / (TILES * TILES); int t = rest % (TILES * TILES);
  int ty = t / TILES, tx = t % TILES;
  int tid = threadIdx.x;
  int og = g * NCO;
  int gx0 = tx * 16 - 1, gy0 = ty * 16 - 1;
  const float* inb = in + (size_t)b * 32 * HS * HS;

  for (int i = tid; i < 32 * 18 * 18; i += 256) {
    int ci = i / 324; int r = i - ci * 324;
    int row = r / 18; int col = r - row * 18;
    int gy = gy0 + row, gx = gx0 + col;
    float v = 0.f;
    if (gy >= 0 && gy < HS && gx >= 0 && gx < HS)
      v = inb[((size_t)ci * HS + gy) * HS + gx];
    s_in[ci][row][col] = v;
  }
  __syncthreads();

  int px = tid & 15, py = tid >> 4;
  float acc[NCO];
#pragma unroll
  for (int o = 0; o < NCO; o++) acc[o] = bias[og + o];

  for (int ci = 0; ci < 32; ci++) {
    float v[9];
#pragma unroll
    for (int di = 0; di < 3; di++)
#pragma unroll
      for (int dj = 0; dj < 3; dj++)
        v[di * 3 + dj] = s_in[ci][py + di][px + dj];
#pragma unroll
    for (int tap = 0; tap < 9; tap++) {
      const float* wrow = wt + (ci * 9 + tap) * 32 + og;
#pragma unroll
      for (int o = 0; o < NCO; o++)
        acc[o] = fmaf(v[tap], wrow[o], acc[o]);
    }
  }

  int gy = ty * 16 + py, gx = tx * 16 + px;
#pragma unroll
  for (int o = 0; o < NCO; o++) {
    float r2 = acc[o];
    if (RELU) r2 = r2 > 0.f ? r2 : 0.01f * r2;
    size_t oi = (((size_t)b * 32 + og + o) * HS + gy) * HS + gx;
    if (RES) r2 += res[oi];
    out[oi] = r2;
  }
}

// ---- expander 1x1 (32->320) + tanh, one thread per (pixel, output).
// ewt layout: (ci, o). wmap layout: (B, Hb, Wb, C, 10) -- pixel-major, coalesced write.
__global__ __launch_bounds__(256) void expander_kernel(
    const float* __restrict__ feat, const float* __restrict__ ewt,
    const float* __restrict__ eb, float* __restrict__ wmap) {
  int idx = blockIdx.x * 256 + threadIdx.x;
  if (idx >= BATCH * 64 * 64 * 320) return;
  int o = idx % 320;
  int pix = idx / 320;
  int wb = pix & 63; int t = pix >> 6; int hb = t & 63; int b = t >> 6;
  const float* fp = feat + (size_t)b * 32 * 64 * 64 + hb * 64 + wb;
  float s = eb[o];
#pragma unroll
  for (int ci = 0; ci < 32; ci++)
    s = fmaf(fp[(size_t)ci * 4096], ewt[ci * 320 + o], s);
  wmap[idx] = tanhf(s);
}

// ---- flying conv: thread = 8 vertical pixels (one hb strip) at one w column.
// Writes fly result to out (b,c,h,w). wmap layout (B,Hb,Wb,C,10).
__global__ __launch_bounds__(256) void fly_kernel(
    const float* __restrict__ x, const float* __restrict__ wmap,
    float* __restrict__ out) {
  int idx = blockIdx.x * 256 + threadIdx.x;  // B * 64 strips * 512 w
  int w = idx & 511; int t = idx >> 9; int strip = t & 63; int b = t >> 6;
  int h0 = strip * 8; int wb = w >> 3;
  const float* wblk = wmap + ((size_t)((b * 64 + strip) * 64 + wb)) * 320;
  const float* xb = x + (size_t)b * 32 * 512 * 512;
  float* ob = out + (size_t)b * 32 * 512 * 512;
  bool wl = (w > 0), wr_ok = (w < 511);

  for (int c = 0; c < 32; c++) {
    const float* xc = xb + (size_t)c * 262144;
    float wv[10];
#pragma unroll
    for (int k = 0; k < 5; k++) {
      float2 p = *reinterpret_cast<const float2*>(wblk + c * 10 + 2 * k);
      wv[2 * k] = p.x; wv[2 * k + 1] = p.y;
    }
    float v[10][3];
#pragma unroll
    for (int r = 0; r < 10; r++) {
      int gr = h0 - 1 + r;
      if (gr < 0 || gr > 511) {
        v[r][0] = 0.f; v[r][1] = 0.f; v[r][2] = 0.f;
      } else {
        const float* row = xc + (size_t)gr * 512 + w;
        v[r][0] = wl ? row[-1] : 0.f;
        v[r][1] = row[0];
        v[r][2] = wr_ok ? row[1] : 0.f;
      }
    }
#pragma unroll
    for (int p = 0; p < 8; p++) {
      float fly = wv[9];
#pragma unroll
      for (int di = 0; di < 3; di++)
#pragma unroll
        for (int dj = 0; dj < 3; dj++)
          fly = fmaf(v[p + di][dj], wv[di * 3 + dj], fly);
      ob[((size_t)c * 512 + h0 + p) * 512 + w] = fly;
    }
  }
}

// ---- final 1x1 conv, IN-PLACE on out buffer. pwt layout (c,o).
// Each thread owns one pixel column (all 32 channels): reads all, then writes all.
__global__ __launch_bounds__(256) void pw_inplace_kernel(
    const float* __restrict__ pwt, const float* __restrict__ pw_b,
    float* __restrict__ out) {
  int idx = blockIdx.x * 256 + threadIdx.x;  // B*512*512
  size_t base = (size_t)(idx >> 18) * 32 * 262144 + (idx & 262143);
  float f[32];
#pragma unroll
  for (int c = 0; c < 32; c++) f[c] = out[base + (size_t)c * 262144];
  float acc[32];
#pragma unroll
  for (int o = 0; o < 32; o++) acc[o] = pw_b[o];
  for (int c = 0; c < 32; c++) {
    const float* wrow = pwt + c * 32;
#pragma unroll
    for (int o = 0; o < 32; o++)
      acc[o] = fmaf(f[c], wrow[o], acc[o]);
  }
#pragma unroll
  for (int o = 0; o < 32; o++) out[base + (size_t)o * 262144] = acc[o];
}

extern "C" void kernel_launch(void* const* d_in, const int* in_sizes, int n_in,
                              void* d_out, int out_size, void* d_ws, size_t ws_size,
                              hipStream_t stream) {
  const float* x     = (const float*)d_in[0];
  const float* pa_w  = (const float*)d_in[1];
  const float* pa_b  = (const float*)d_in[2];
  const float* exp_w = (const float*)d_in[3];
  const float* exp_b = (const float*)d_in[4];
  const float* pw_w  = (const float*)d_in[5];
  const float* pw_b  = (const float*)d_in[6];
  float* out = (float*)d_out;
  float* ws  = (float*)d_ws;

  float* feat0 = ws;                 // 4*32*128*128 = 2,097,152
  float* tmpA  = feat0 + 2097152;    // 2,097,152
  float* feat1 = tmpA + 2097152;     // 4*32*64*64 = 524,288
  float* tmpB  = feat1 + 524288;     // 524,288
  float* wmap  = tmpB + 524288;      // 4*64*64*32*10 = 5,242,880
  float* wt    = wmap + 5242880;     // 73,728
  float* ewt   = wt + 73728;         // 10,240
  float* pwt   = ewt + 10240;        // 1,024

  hipLaunchKernelGGL(transpose_w_kernel, dim3(288), dim3(256), 0, stream, pa_w, wt);
  hipLaunchKernelGGL(transpose_ew_kernel, dim3(40), dim3(256), 0, stream, exp_w, ewt);
  hipLaunchKernelGGL(transpose_pw_kernel, dim3(4), dim3(256), 0, stream, pw_w, pwt);
  hipLaunchKernelGGL(avgpool4_kernel, dim3(8192), dim3(256), 0, stream, x, feat0);

  // predictors @128: 8 co per block -> 4*64*4 = 1024 blocks
  for (int i = 0; i < 2; i++) {
    const float* w1 = wt + (size_t)(i * 2 + 0) * 9216;
    const float* b1 = pa_b + (i * 2 + 0) * 32;
    const float* w2 = wt + (size_t)(i * 2 + 1) * 9216;
    const float* b2 = pa_b + (i * 2 + 1) * 32;
    hipLaunchKernelGGL((conv3x3_kernel<128, 8, true, false>), dim3(1024), dim3(256), 0, stream,
                       feat0, w1, b1, nullptr, tmpA);
    hipLaunchKernelGGL((conv3x3_kernel<128, 8, false, true>), dim3(1024), dim3(256), 0, stream,
                       tmpA, w2, b2, feat0, feat0);
  }

  hipLaunchKernelGGL(avgpool2_kernel, dim3(2048), dim3(256), 0, stream, feat0, feat1);

  // predictors @64: 4 co per block -> 4*16*8 = 512 blocks
  for (int i = 2; i < 4; i++) {
    const float* w1 = wt + (size_t)(i * 2 + 0) * 9216;
    const float* b1 = pa_b + (i * 2 + 0) * 32;
    const float* w2 = wt + (size_t)(i * 2 + 1) * 9216;
    const float* b2 = pa_b + (i * 2 + 1) * 32;
    hipLaunchKernelGGL((conv3x3_kernel<64, 4, true, false>), dim3(512), dim3(256), 0, stream,
                       feat1, w1, b1, nullptr, tmpB);
    hipLaunchKernelGGL((conv3x3_kernel<64, 4, false, true>), dim3(512), dim3(256), 0, stream,
                       tmpB, w2, b2, feat1, feat1);
  }

  hipLaunchKernelGGL(expander_kernel, dim3(20480), dim3(256), 0, stream, feat1, ewt, exp_b, wmap);
  hipLaunchKernelGGL(fly_kernel, dim3(512), dim3(256), 0, stream, x, wmap, out);
  hipLaunchKernelGGL(pw_inplace_kernel, dim3(4096), dim3(256), 0, stream, pwt, pw_b, out);
}

// Round 4
// 526.607 us; speedup vs baseline: 1.8137x; 1.0971x over previous
//
#include <hip/hip_runtime.h>

// MalleConv: all f32.
// Inputs: x(4,32,512,512), pa_w(4,2,32,32,3,3), pa_b(4,2,32),
//         exp_w(320,32,1,1), exp_b(320), pw_w(32,32,1,1), pw_b(32)
// Output: (4,32,512,512) f32

#define BATCH 4
#define NCH 32

__device__ __forceinline__ float fast_tanh(float s) {
  float e = __expf(2.f * s);
  return fmaf(-2.f, __builtin_amdgcn_rcpf(e + 1.f), 1.f);
}

// ---- prep: pa_w (8,co,ci,9)->(8,ci,9,co); exp_w (320,32)->(32,320); pw_w (o,c)->(c,o)
__global__ void prep_kernel(const float* __restrict__ pa_w, const float* __restrict__ exp_w,
                            const float* __restrict__ pw_w, float* __restrict__ wt,
                            float* __restrict__ ewt, float* __restrict__ pwt) {
  int i = blockIdx.x * 256 + threadIdx.x;
  if (i < 73728) {
    int tap = i % 9; int t = i / 9;
    int ci = t & 31; t >>= 5;
    int co = t & 31; int layer = t >> 5;
    wt[((layer * 32 + ci) * 9 + tap) * 32 + co] = pa_w[i];
  } else if (i < 83968) {
    int j = i - 73728; int ci = j & 31; int o = j >> 5;
    ewt[ci * 320 + o] = exp_w[j];
  } else if (i < 84992) {
    int j = i - 83968; int c = j & 31; int o = j >> 5;
    pwt[c * 32 + o] = pw_w[j];
  }
}

// ---- avgpool k=4: (B,C,512,512) -> (B,C,128,128)
__global__ void avgpool4_kernel(const float* __restrict__ x, float* __restrict__ out) {
  int idx = blockIdx.x * 256 + threadIdx.x;
  if (idx >= BATCH * NCH * 128 * 128) return;
  int ow = idx & 127; int t = idx >> 7; int oh = t & 127; int bc = t >> 7;
  const float* src = x + ((size_t)(bc * 512 + oh * 4)) * 512 + ow * 4;
  float s = 0.f;
#pragma unroll
  for (int r = 0; r < 4; r++) {
    float4 v = *reinterpret_cast<const float4*>(src + (size_t)r * 512);
    s += v.x + v.y + v.z + v.w;
  }
  out[idx] = s * 0.0625f;
}

// ---- avgpool k=2: (B,C,128,128) -> (B,C,64,64)
__global__ void avgpool2_kernel(const float* __restrict__ in, float* __restrict__ out) {
  int idx = blockIdx.x * 256 + threadIdx.x;
  if (idx >= BATCH * NCH * 64 * 64) return;
  int ow = idx & 63; int t = idx >> 6; int oh = t & 63; int bc = t >> 6;
  const float* src = in + (size_t)(bc * 128 + oh * 2) * 128 + ow * 2;
  float2 a = *reinterpret_cast<const float2*>(src);
  float2 b = *reinterpret_cast<const float2*>(src + 128);
  out[idx] = (a.x + a.y + b.x + b.y) * 0.25f;
}

// ---- conv3x3 (same padding), C=32->NCO per block, optional leaky-relu, optional residual.
// wt layout: (ci,9,co). GROUPS = 32/NCO blocks per tile for output-channel parallelism.
template <int HS, int NCO, bool RELU, bool RES>
__global__ __launch_bounds__(256) void conv3x3_kernel(
    const float* __restrict__ in, const float* __restrict__ wt,
    const float* __restrict__ bias, const float* __restrict__ res,
    float* __restrict__ out) {
  constexpr int TILES = HS / 16;
  constexpr int GROUPS = 32 / NCO;
  __shared__ float s_in[32][18][18];
  int blk = blockIdx.x;
  int g = blk % GROUPS; int rest = blk / GROUPS;
  int b = rest / (TILES * TILES); int t = rest % (TILES * TILES);
  int ty = t / TILES, tx = t % TILES;
  int tid = threadIdx.x;
  int og = g * NCO;
  int gx0 = tx * 16 - 1, gy0 = ty * 16 - 1;
  const float* inb = in + (size_t)b * 32 * HS * HS;

  for (int i = tid; i < 32 * 18 * 18; i += 256) {
    int ci = i / 324; int r = i - ci * 324;
    int row = r / 18; int col = r - row * 18;
    int gy = gy0 + row, gx = gx0 + col;
    float v = 0.f;
    if (gy >= 0 && gy < HS && gx >= 0 && gx < HS)
      v = inb[((size_t)ci * HS + gy) * HS + gx];
    s_in[ci][row][col] = v;
  }
  __syncthreads();

  int px = tid & 15, py = tid >> 4;
  float acc[NCO];
#pragma unroll
  for (int o = 0; o < NCO; o++) acc[o] = bias[og + o];

  for (int ci = 0; ci < 32; ci++) {
    float v[9];
#pragma unroll
    for (int di = 0; di < 3; di++)
#pragma unroll
      for (int dj = 0; dj < 3; dj++)
        v[di * 3 + dj] = s_in[ci][py + di][px + dj];
#pragma unroll
    for (int tap = 0; tap < 9; tap++) {
      const float* wrow = wt + (ci * 9 + tap) * 32 + og;
#pragma unroll
      for (int o = 0; o < NCO; o++)
        acc[o] = fmaf(v[tap], wrow[o], acc[o]);
    }
  }

  int gy = ty * 16 + py, gx = tx * 16 + px;
#pragma unroll
  for (int o = 0; o < NCO; o++) {
    float r2 = acc[o];
    if (RELU) r2 = r2 > 0.f ? r2 : 0.01f * r2;
    size_t oi = (((size_t)b * 32 + og + o) * HS + gy) * HS + gx;
    if (RES) r2 += res[oi];
    out[oi] = r2;
  }
}

// ---- expander 1x1 (32->320) + fast tanh.
// Thread = (4-pixel quad, o). wmap layout: (B, Hb, 320, Wb) -- tap-major rows,
// so fused kernel's weight read is coalesced across wb lanes.
__global__ __launch_bounds__(256) void expander_kernel(
    const float* __restrict__ feat, const float* __restrict__ ewt,
    const float* __restrict__ eb, float* __restrict__ wmap) {
  int idx = blockIdx.x * 256 + threadIdx.x;  // 4*64*16*320 = 1,310,720
  int wq = idx & 15; int t = idx >> 4;
  int o = t % 320; int rest = t / 320;
  int hb = rest & 63; int b = rest >> 6;
  const float* fp = feat + (size_t)b * 131072 + hb * 64 + wq * 4;
  float s0 = eb[o];
  float s1 = s0, s2 = s0, s3 = s0;
#pragma unroll 8
  for (int ci = 0; ci < 32; ci++) {
    float4 f = *reinterpret_cast<const float4*>(fp + (size_t)ci * 4096);
    float wv = ewt[ci * 320 + o];
    s0 = fmaf(f.x, wv, s0); s1 = fmaf(f.y, wv, s1);
    s2 = fmaf(f.z, wv, s2); s3 = fmaf(f.w, wv, s3);
  }
  float4 r;
  r.x = fast_tanh(s0); r.y = fast_tanh(s1);
  r.z = fast_tanh(s2); r.w = fast_tanh(s3);
  *reinterpret_cast<float4*>(wmap + (size_t)((b * 64 + hb) * 320 + o) * 64 + wq * 4) = r;
}

// ---- fused flying conv + final 1x1. Thread = 4 horizontal pixels.
// wmap layout (B, Hb, 320, Wb): per-tap loads are wave-coalesced dwords.
__global__ __launch_bounds__(256) void fused_fly_pw_kernel(
    const float* __restrict__ x, const float* __restrict__ wmap,
    const float* __restrict__ pwt, const float* __restrict__ pw_b,
    float* __restrict__ out) {
  int idx = blockIdx.x * 256 + threadIdx.x;  // B*512*128 = 262,144
  int wq = idx & 127; int t = idx >> 7; int h = t & 511; int b = t >> 9;
  int w0 = wq * 4;
  int hb = h >> 3, wb = w0 >> 3;
  const float* wbase = wmap + (size_t)(b * 64 + hb) * 320 * 64 + wb;
  const float* xb = x + (size_t)b * 32 * 262144;

  float4 acc[32];
#pragma unroll
  for (int o = 0; o < 32; o++) {
    float bv = pw_b[o];
    acc[o].x = bv; acc[o].y = bv; acc[o].z = bv; acc[o].w = bv;
  }

  for (int c = 0; c < 32; c++) {
    float wv[10];
#pragma unroll
    for (int k = 0; k < 10; k++)
      wv[k] = wbase[(size_t)(c * 10 + k) * 64];
    float fly0 = wv[9], fly1 = wv[9], fly2 = wv[9], fly3 = wv[9];
    const float* xc = xb + (size_t)c * 262144;
#pragma unroll
    for (int di = 0; di < 3; di++) {
      int hh = h + di - 1;
      if (hh < 0 || hh >= 512) continue;
      const float* rp = xc + (size_t)hh * 512 + w0;
      float xl = (w0 > 0) ? rp[-1] : 0.f;
      float4 xm = *reinterpret_cast<const float4*>(rp);
      float xr = (w0 < 508) ? rp[4] : 0.f;
      float wa = wv[di * 3 + 0], wbv = wv[di * 3 + 1], wc = wv[di * 3 + 2];
      fly0 = fmaf(xl,   wa, fly0); fly0 = fmaf(xm.x, wbv, fly0); fly0 = fmaf(xm.y, wc, fly0);
      fly1 = fmaf(xm.x, wa, fly1); fly1 = fmaf(xm.y, wbv, fly1); fly1 = fmaf(xm.z, wc, fly1);
      fly2 = fmaf(xm.y, wa, fly2); fly2 = fmaf(xm.z, wbv, fly2); fly2 = fmaf(xm.w, wc, fly2);
      fly3 = fmaf(xm.z, wa, fly3); fly3 = fmaf(xm.w, wbv, fly3); fly3 = fmaf(xr,   wc, fly3);
    }
    const float* prow = pwt + c * 32;
#pragma unroll
    for (int o = 0; o < 32; o++) {
      float pw = prow[o];
      acc[o].x = fmaf(fly0, pw, acc[o].x);
      acc[o].y = fmaf(fly1, pw, acc[o].y);
      acc[o].z = fmaf(fly2, pw, acc[o].z);
      acc[o].w = fmaf(fly3, pw, acc[o].w);
    }
  }
  float* ob = out + (size_t)b * 32 * 262144 + (size_t)h * 512 + w0;
#pragma unroll
  for (int o = 0; o < 32; o++)
    *reinterpret_cast<float4*>(ob + (size_t)o * 262144) = acc[o];
}

extern "C" void kernel_launch(void* const* d_in, const int* in_sizes, int n_in,
                              void* d_out, int out_size, void* d_ws, size_t ws_size,
                              hipStream_t stream) {
  const float* x     = (const float*)d_in[0];
  const float* pa_w  = (const float*)d_in[1];
  const float* pa_b  = (const float*)d_in[2];
  const float* exp_w = (const float*)d_in[3];
  const float* exp_b = (const float*)d_in[4];
  const float* pw_w  = (const float*)d_in[5];
  const float* pw_b  = (const float*)d_in[6];
  float* out = (float*)d_out;
  float* ws  = (float*)d_ws;

  float* feat0 = ws;                 // 4*32*128*128 = 2,097,152
  float* tmpA  = feat0 + 2097152;    // 2,097,152
  float* feat1 = tmpA + 2097152;     // 4*32*64*64 = 524,288
  float* tmpB  = feat1 + 524288;     // 524,288
  float* wmap  = tmpB + 524288;      // 4*64*320*64 = 5,242,880
  float* wt    = wmap + 5242880;     // 73,728
  float* ewt   = wt + 73728;         // 10,240
  float* pwt   = ewt + 10240;        // 1,024

  hipLaunchKernelGGL(prep_kernel, dim3(332), dim3(256), 0, stream, pa_w, exp_w, pw_w, wt, ewt, pwt);
  hipLaunchKernelGGL(avgpool4_kernel, dim3(8192), dim3(256), 0, stream, x, feat0);

  // predictors @128: 8 co per block -> 4*64*4 = 1024 blocks
  for (int i = 0; i < 2; i++) {
    const float* w1 = wt + (size_t)(i * 2 + 0) * 9216;
    const float* b1 = pa_b + (i * 2 + 0) * 32;
    const float* w2 = wt + (size_t)(i * 2 + 1) * 9216;
    const float* b2 = pa_b + (i * 2 + 1) * 32;
    hipLaunchKernelGGL((conv3x3_kernel<128, 8, true, false>), dim3(1024), dim3(256), 0, stream,
                       feat0, w1, b1, nullptr, tmpA);
    hipLaunchKernelGGL((conv3x3_kernel<128, 8, false, true>), dim3(1024), dim3(256), 0, stream,
                       tmpA, w2, b2, feat0, feat0);
  }

  hipLaunchKernelGGL(avgpool2_kernel, dim3(2048), dim3(256), 0, stream, feat0, feat1);

  // predictors @64: 4 co per block -> 4*16*8 = 512 blocks
  for (int i = 2; i < 4; i++) {
    const float* w1 = wt + (size_t)(i * 2 + 0) * 9216;
    const float* b1 = pa_b + (i * 2 + 0) * 32;
    const float* w2 = wt + (size_t)(i * 2 + 1) * 9216;
    const float* b2 = pa_b + (i * 2 + 1) * 32;
    hipLaunchKernelGGL((conv3x3_kernel<64, 4, true, false>), dim3(512), dim3(256), 0, stream,
                       feat1, w1, b1, nullptr, tmpB);
    hipLaunchKernelGGL((conv3x3_kernel<64, 4, false, true>), dim3(512), dim3(256), 0, stream,
                       tmpB, w2, b2, feat1, feat1);
  }

  hipLaunchKernelGGL(expander_kernel, dim3(5120), dim3(256), 0, stream, feat1, ewt, exp_b, wmap);
  hipLaunchKernelGGL(fused_fly_pw_kernel, dim3(1024), dim3(256), 0, stream,
                     x, wmap, pwt, pw_b, out);
}

// Round 5
// 517.939 us; speedup vs baseline: 1.8440x; 1.0167x over previous
//
#include <hip/hip_runtime.h>

// MalleConv: all f32.
// Inputs: x(4,32,512,512), pa_w(4,2,32,32,3,3), pa_b(4,2,32),
//         exp_w(320,32,1,1), exp_b(320), pw_w(32,32,1,1), pw_b(32)
// Output: (4,32,512,512) f32

#define BATCH 4
#define NCH 32

__device__ __forceinline__ float fast_tanh(float s) {
  float e = __expf(2.f * s);
  return fmaf(-2.f, __builtin_amdgcn_rcpf(e + 1.f), 1.f);
}

// ---- prep: pa_w (8,co,ci,9)->(8,ci,9,co); exp_w (320,32)->(32,320); pw_w (o,c)->(c,o)
__global__ void prep_kernel(const float* __restrict__ pa_w, const float* __restrict__ exp_w,
                            const float* __restrict__ pw_w, float* __restrict__ wt,
                            float* __restrict__ ewt, float* __restrict__ pwt) {
  int i = blockIdx.x * 256 + threadIdx.x;
  if (i < 73728) {
    int tap = i % 9; int t = i / 9;
    int ci = t & 31; t >>= 5;
    int co = t & 31; int layer = t >> 5;
    wt[((layer * 32 + ci) * 9 + tap) * 32 + co] = pa_w[i];
  } else if (i < 83968) {
    int j = i - 73728; int ci = j & 31; int o = j >> 5;
    ewt[ci * 320 + o] = exp_w[j];
  } else if (i < 84992) {
    int j = i - 83968; int c = j & 31; int o = j >> 5;
    pwt[c * 32 + o] = pw_w[j];
  }
}

// ---- avgpool k=4: (B,C,512,512) -> (B,C,128,128)
__global__ void avgpool4_kernel(const float* __restrict__ x, float* __restrict__ out) {
  int idx = blockIdx.x * 256 + threadIdx.x;
  if (idx >= BATCH * NCH * 128 * 128) return;
  int ow = idx & 127; int t = idx >> 7; int oh = t & 127; int bc = t >> 7;
  const float* src = x + ((size_t)(bc * 512 + oh * 4)) * 512 + ow * 4;
  float s = 0.f;
#pragma unroll
  for (int r = 0; r < 4; r++) {
    float4 v = *reinterpret_cast<const float4*>(src + (size_t)r * 512);
    s += v.x + v.y + v.z + v.w;
  }
  out[idx] = s * 0.0625f;
}

// ---- avgpool k=2: (B,C,128,128) -> (B,C,64,64)
__global__ void avgpool2_kernel(const float* __restrict__ in, float* __restrict__ out) {
  int idx = blockIdx.x * 256 + threadIdx.x;
  if (idx >= BATCH * NCH * 64 * 64) return;
  int ow = idx & 63; int t = idx >> 6; int oh = t & 63; int bc = t >> 6;
  const float* src = in + (size_t)(bc * 128 + oh * 2) * 128 + ow * 2;
  float2 a = *reinterpret_cast<const float2*>(src);
  float2 b = *reinterpret_cast<const float2*>(src + 128);
  out[idx] = (a.x + a.y + b.x + b.y) * 0.25f;
}

// ---- conv3x3 (same padding), C=32->NCO per block, optional leaky-relu, optional residual.
// wt layout: (ci,9,co). GROUPS = 32/NCO blocks per tile for output-channel parallelism.
template <int HS, int NCO, bool RELU, bool RES>
__global__ __launch_bounds__(256) void conv3x3_kernel(
    const float* __restrict__ in, const float* __restrict__ wt,
    const float* __restrict__ bias, const float* __restrict__ res,
    float* __restrict__ out) {
  constexpr int TILES = HS / 16;
  constexpr int GROUPS = 32 / NCO;
  __shared__ float s_in[32][18][18];
  int blk = blockIdx.x;
  int g = blk % GROUPS; int rest = blk / GROUPS;
  int b = rest / (TILES * TILES); int t = rest % (TILES * TILES);
  int ty = t / TILES, tx = t % TILES;
  int tid = threadIdx.x;
  int og = g * NCO;
  int gx0 = tx * 16 - 1, gy0 = ty * 16 - 1;
  const float* inb = in + (size_t)b * 32 * HS * HS;

  for (int i = tid; i < 32 * 18 * 18; i += 256) {
    int ci = i / 324; int r = i - ci * 324;
    int row = r / 18; int col = r - row * 18;
    int gy = gy0 + row, gx = gx0 + col;
    float v = 0.f;
    if (gy >= 0 && gy < HS && gx >= 0 && gx < HS)
      v = inb[((size_t)ci * HS + gy) * HS + gx];
    s_in[ci][row][col] = v;
  }
  __syncthreads();

  int px = tid & 15, py = tid >> 4;
  float acc[NCO];
#pragma unroll
  for (int o = 0; o < NCO; o++) acc[o] = bias[og + o];

  for (int ci = 0; ci < 32; ci++) {
    float v[9];
#pragma unroll
    for (int di = 0; di < 3; di++)
#pragma unroll
      for (int dj = 0; dj < 3; dj++)
        v[di * 3 + dj] = s_in[ci][py + di][px + dj];
#pragma unroll
    for (int tap = 0; tap < 9; tap++) {
      const float* wrow = wt + (ci * 9 + tap) * 32 + og;
#pragma unroll
      for (int o = 0; o < NCO; o++)
        acc[o] = fmaf(v[tap], wrow[o], acc[o]);
    }
  }

  int gy = ty * 16 + py, gx = tx * 16 + px;
#pragma unroll
  for (int o = 0; o < NCO; o++) {
    float r2 = acc[o];
    if (RELU) r2 = r2 > 0.f ? r2 : 0.01f * r2;
    size_t oi = (((size_t)b * 32 + og + o) * HS + gy) * HS + gx;
    if (RES) r2 += res[oi];
    out[oi] = r2;
  }
}

// ---- expander 1x1 (32->320) + fast tanh.
// Thread = (4-pixel quad, o). wmap layout: (B, Hb, 320, Wb) -- tap-major rows,
// so fused kernel's weight read is coalesced across wb lanes.
__global__ __launch_bounds__(256) void expander_kernel(
    const float* __restrict__ feat, const float* __restrict__ ewt,
    const float* __restrict__ eb, float* __restrict__ wmap) {
  int idx = blockIdx.x * 256 + threadIdx.x;  // 4*64*16*320 = 1,310,720
  int wq = idx & 15; int t = idx >> 4;
  int o = t % 320; int rest = t / 320;
  int hb = rest & 63; int b = rest >> 6;
  const float* fp = feat + (size_t)b * 131072 + hb * 64 + wq * 4;
  float s0 = eb[o];
  float s1 = s0, s2 = s0, s3 = s0;
#pragma unroll 8
  for (int ci = 0; ci < 32; ci++) {
    float4 f = *reinterpret_cast<const float4*>(fp + (size_t)ci * 4096);
    float wv = ewt[ci * 320 + o];
    s0 = fmaf(f.x, wv, s0); s1 = fmaf(f.y, wv, s1);
    s2 = fmaf(f.z, wv, s2); s3 = fmaf(f.w, wv, s3);
  }
  float4 r;
  r.x = fast_tanh(s0); r.y = fast_tanh(s1);
  r.z = fast_tanh(s2); r.w = fast_tanh(s3);
  *reinterpret_cast<float4*>(wmap + (size_t)((b * 64 + hb) * 320 + o) * 64 + wq * 4) = r;
}

// ---- fused flying conv + final 1x1, v2.
// Workgroup tile: 8 rows (one hb) x 64 cols (8 wb blocks). 2 px/thread.
// wmap staged in LDS [8][322] (pad: 8B-aligned rows, conflict-free b64 reads).
__global__ __launch_bounds__(256, 4) void fused_fly_pw_kernel(
    const float* __restrict__ x, const float* __restrict__ wmap,
    const float* __restrict__ pwt, const float* __restrict__ pw_b,
    float* __restrict__ out) {
  __shared__ float s_w[8][322];
  int blk = blockIdx.x;  // ((b*64+hb)*8 + wt)
  int wtile = blk & 7; int t = blk >> 3; int hb = t & 63; int b = t >> 6;
  int tid = threadIdx.x;

  const float* wsrc = wmap + (size_t)(b * 64 + hb) * 320 * 64 + wtile * 8;
#pragma unroll
  for (int j = 0; j < 10; j++) {
    int idx = j * 256 + tid;
    int tap = idx >> 3, wb8 = idx & 7;
    s_w[wb8][tap] = wsrc[(size_t)tap * 64 + wb8];
  }
  __syncthreads();

  int cp = tid & 31, row = tid >> 5;
  int h = hb * 8 + row;
  int w0 = wtile * 64 + cp * 2;
  int wbl = cp >> 2;
  const float* xb = x + (size_t)b * 32 * 262144;

  float2 acc[32];
#pragma unroll
  for (int o = 0; o < 32; o++) {
    float bv = pw_b[o];
    acc[o].x = bv; acc[o].y = bv;
  }

  for (int c = 0; c < 32; c++) {
    const float2* wr2 = reinterpret_cast<const float2*>(&s_w[wbl][c * 10]);
    float2 w01 = wr2[0], w23 = wr2[1], w45 = wr2[2], w67 = wr2[3], w89 = wr2[4];
    float wv[9];
    wv[0] = w01.x; wv[1] = w01.y; wv[2] = w23.x;
    wv[3] = w23.y; wv[4] = w45.x; wv[5] = w45.y;
    wv[6] = w67.x; wv[7] = w67.y; wv[8] = w89.x;
    float fly0 = w89.y, fly1 = w89.y;  // bias tap

    const float* xc = xb + (size_t)c * 262144;
#pragma unroll
    for (int di = 0; di < 3; di++) {
      int hh = h + di - 1;
      if (hh < 0 || hh >= 512) continue;
      const float* rp = xc + (size_t)hh * 512 + w0;
      float xl = (w0 > 0) ? rp[-1] : 0.f;
      float2 xm = *reinterpret_cast<const float2*>(rp);
      float xr = (w0 < 510) ? rp[2] : 0.f;
      float wa = wv[di * 3 + 0], wbv = wv[di * 3 + 1], wc = wv[di * 3 + 2];
      fly0 = fmaf(xl,   wa, fly0); fly0 = fmaf(xm.x, wbv, fly0); fly0 = fmaf(xm.y, wc, fly0);
      fly1 = fmaf(xm.x, wa, fly1); fly1 = fmaf(xm.y, wbv, fly1); fly1 = fmaf(xr,   wc, fly1);
    }
    const float* prow = pwt + c * 32;
#pragma unroll
    for (int o = 0; o < 32; o++) {
      float pw = prow[o];
      acc[o].x = fmaf(fly0, pw, acc[o].x);
      acc[o].y = fmaf(fly1, pw, acc[o].y);
    }
  }
  float* ob = out + (size_t)b * 32 * 262144 + (size_t)h * 512 + w0;
#pragma unroll
  for (int o = 0; o < 32; o++)
    *reinterpret_cast<float2*>(ob + (size_t)o * 262144) = acc[o];
}

extern "C" void kernel_launch(void* const* d_in, const int* in_sizes, int n_in,
                              void* d_out, int out_size, void* d_ws, size_t ws_size,
                              hipStream_t stream) {
  const float* x     = (const float*)d_in[0];
  const float* pa_w  = (const float*)d_in[1];
  const float* pa_b  = (const float*)d_in[2];
  const float* exp_w = (const float*)d_in[3];
  const float* exp_b = (const float*)d_in[4];
  const float* pw_w  = (const float*)d_in[5];
  const float* pw_b  = (const float*)d_in[6];
  float* out = (float*)d_out;
  float* ws  = (float*)d_ws;

  float* feat0 = ws;                 // 4*32*128*128 = 2,097,152
  float* tmpA  = feat0 + 2097152;    // 2,097,152
  float* feat1 = tmpA + 2097152;     // 4*32*64*64 = 524,288
  float* tmpB  = feat1 + 524288;     // 524,288
  float* wmap  = tmpB + 524288;      // 4*64*320*64 = 5,242,880
  float* wt    = wmap + 5242880;     // 73,728
  float* ewt   = wt + 73728;         // 10,240
  float* pwt   = ewt + 10240;        // 1,024

  hipLaunchKernelGGL(prep_kernel, dim3(332), dim3(256), 0, stream, pa_w, exp_w, pw_w, wt, ewt, pwt);
  hipLaunchKernelGGL(avgpool4_kernel, dim3(8192), dim3(256), 0, stream, x, feat0);

  // predictors @128: 8 co per block -> 4*64*4 = 1024 blocks
  for (int i = 0; i < 2; i++) {
    const float* w1 = wt + (size_t)(i * 2 + 0) * 9216;
    const float* b1 = pa_b + (i * 2 + 0) * 32;
    const float* w2 = wt + (size_t)(i * 2 + 1) * 9216;
    const float* b2 = pa_b + (i * 2 + 1) * 32;
    hipLaunchKernelGGL((conv3x3_kernel<128, 8, true, false>), dim3(1024), dim3(256), 0, stream,
                       feat0, w1, b1, nullptr, tmpA);
    hipLaunchKernelGGL((conv3x3_kernel<128, 8, false, true>), dim3(1024), dim3(256), 0, stream,
                       tmpA, w2, b2, feat0, feat0);
  }

  hipLaunchKernelGGL(avgpool2_kernel, dim3(2048), dim3(256), 0, stream, feat0, feat1);

  // predictors @64: 4 co per block -> 4*16*8 = 512 blocks
  for (int i = 2; i < 4; i++) {
    const float* w1 = wt + (size_t)(i * 2 + 0) * 9216;
    const float* b1 = pa_b + (i * 2 + 0) * 32;
    const float* w2 = wt + (size_t)(i * 2 + 1) * 9216;
    const float* b2 = pa_b + (i * 2 + 1) * 32;
    hipLaunchKernelGGL((conv3x3_kernel<64, 4, true, false>), dim3(512), dim3(256), 0, stream,
                       feat1, w1, b1, nullptr, tmpB);
    hipLaunchKernelGGL((conv3x3_kernel<64, 4, false, true>), dim3(512), dim3(256), 0, stream,
                       tmpB, w2, b2, feat1, feat1);
  }

  hipLaunchKernelGGL(expander_kernel, dim3(5120), dim3(256), 0, stream, feat1, ewt, exp_b, wmap);
  hipLaunchKernelGGL(fused_fly_pw_kernel, dim3(2048), dim3(256), 0, stream,
                     x, wmap, pwt, pw_b, out);
}